// Round 1
// 420.107 us; speedup vs baseline: 1.2116x; 1.2116x over previous
//
#include <hip/hip_runtime.h>
#include <hip/hip_fp16.h>

// GaussianBlur as banded-Toeplitz GEMM on matrix cores.
// R3: both passes use v_mfma_f32_32x32x16_f16. Weight fragments are built
// from a pair-duplicated half2 table (w2) in LDS so 8-consecutive-half
// fragments at any parity are 4 aligned ds_read_b32. Image fragments are
// single ds_read_b128 from chunk-XOR-swizzled LDS tiles (pass1: transposed
// [x][i] staging; pass2: row-major with reflected x-halo).
// ws: [0,256) rad | [1024, 58368) gw2 | [65536, +100663296) tmp f16.

#define B_   64
#define C_   3
#define H_   512
#define W_   512
#define RMAX 80
#define NW   224     // w2 entries (half2 pairs), d in [-112, 111]
#define WOFF 112     // w2 half-index of d = 0
#define RROW 288     // LDS halfs along conv axis (96 + 16*ns_max)
#define SROW 64      // LDS rows (x-cols pass1 / y-rows pass2)

typedef float    f32x16 __attribute__((ext_vector_type(16)));
typedef _Float16 f16x8  __attribute__((ext_vector_type(8)));

__device__ __forceinline__ int refl(int g) {
    int a = g < 0 ? -g : g;        // reflect (no edge repeat): -1 -> 1
    int c = 1022 - a;              // 2*(H-1) - a
    return a < c ? a : c;
}

__global__ __launch_bounds__(256) void k_weights(const float* __restrict__ sig,
                                                 const int* __restrict__ steps,
                                                 int* __restrict__ rad,
                                                 unsigned int* __restrict__ gw2) {
    const int b = blockIdx.x;
    const float sigma = sig[steps[b]] + 1e-6f;
    const int t = (int)threadIdx.x;
    const int d = t - 128;                 // covers [-128, 127] >= [-80, 80]
    float e = 0.f;
    if (d >= -RMAX && d <= RMAX) {
        const float u = (float)d / sigma;
        e = expf(-0.5f * u * u);
    }
    __shared__ float red[256];
    __shared__ float wv[256];
    red[t] = e;
    __syncthreads();
    for (int s = 128; s > 0; s >>= 1) {
        if (t < s) red[t] += red[t + s];
        __syncthreads();
    }
    const float inv = 1.0f / red[0];
    int r = (int)ceilf(6.0f * sigma);      // tail beyond 6 sigma < 7e-10
    if (r > RMAX) r = RMAX;
    if (r < 1)    r = 1;
    wv[t] = (d >= -r && d <= r) ? e * inv : 0.f;
    __syncthreads();
    if (t < NW) {
        // w2[t] = halves ( W(t-112), W(t-111) ); wv index = d + 128
        const __half h0 = __float2half(wv[t + 16]);
        const __half h1 = __float2half(wv[t + 17]);
        gw2[b * NW + t] = (unsigned int)__half_as_ushort(h0) |
                          ((unsigned int)__half_as_ushort(h1) << 16);
    }
    if (t == 0) rad[b] = r;
}

// ---------------- vertical pass (MFMA) ----------------
// Block: (bc, y0 = 128-row chunk, x0 = 64-col strip). LDS holds the input
// window transposed: sh[x][i'], i' = global_row - (y0 - r_pad), f16,
// 16B-chunk index XOR-swizzled by (x & 3). Wave w = y-tile tau (32 rows),
// each wave does both 32-col N-tiles sharing one Toeplitz A-fragment.
__global__ __launch_bounds__(256, 4) void k_pass1(const float* __restrict__ x,
                                                  const unsigned int* __restrict__ gw2,
                                                  const int* __restrict__ rad,
                                                  __half* __restrict__ tmp) {
    __shared__ __align__(16) unsigned short sh[SROW * RROW];  // 36864 B
    __shared__ unsigned int w2v[NW];                          // 896 B
    const int tid = threadIdx.x;
    const int bid = blockIdx.x;
    const int bc  = bid >> 5;
    const int rem = bid & 31;
    const int y0  = (rem >> 3) << 7;       // 0,128,256,384
    const int x0  = (rem & 7) << 6;        // 0..448 step 64
    const int b   = bc / C_;
    const size_t img = (size_t)bc * (H_ * (size_t)W_);

    const int r  = rad[b];                 // block-uniform
    const int rp = (r + 7) & ~7;           // r_pad (8-aligned)
    const int ns = (r + rp + 32 + 15) >> 4;  // K-steps (K = 16*ns >= r+rp+32)
    const int Rr = 96 + 16 * ns;           // staged rows (<= 288)
    const int ystart = y0 - rp;

    if (tid < NW) w2v[tid] = gw2[b * NW + tid];

    {   // stage transposed + reflected: 16 row-pairs x 64 cols per sweep
        const int p0 = tid & 15;
        const int x4 = tid >> 4;           // 0..15 -> cols x4*4 .. +3
        const float* gsrc = x + img + (size_t)(x0 + x4 * 4);
        const int i7 = (2 * p0) & 7;       // (i0 & 7) is invariant per thread
        for (int pr = p0; 2 * pr < Rr; pr += 16) {
            const int i0 = 2 * pr;
            const int gy0 = refl(ystart + i0);
            const int gy1 = refl(ystart + i0 + 1);
            const float4 va = *(const float4*)(gsrc + (size_t)gy0 * W_);
            const float4 vb = *(const float4*)(gsrc + (size_t)gy1 * W_);
            const int c = i0 >> 3;
            #pragma unroll
            for (int q = 0; q < 4; ++q) {
                const int xq = x4 * 4 + q;
                const int hidx = xq * RROW + ((c ^ (xq & 3)) << 3) + i7;
                const float fa = q == 0 ? va.x : q == 1 ? va.y : q == 2 ? va.z : va.w;
                const float fb = q == 0 ? vb.x : q == 1 ? vb.y : q == 2 ? vb.z : vb.w;
                *(__half2*)(sh + hidx) = __floats2half2_rn(fa, fb);  // rows (i0, i0+1)
            }
        }
    }
    __syncthreads();

    const int l   = tid & 63;
    const int tau = tid >> 6;              // wave id = y-tile
    const int m   = l & 31;                // A row / B col / D col
    const int g   = l >> 5;                // k-group (k = 8g + j)
    const int ebase = WOFF + 8 * g - rp - m;     // w2 entry of frag half j=0
    const int cb0 = 4 * tau + g;           // i'-chunk = 4*tau + 2s + g
    const int key = m & 3;
    const int bb0 = m * RROW;              // N-tile 0: x = m
    const int bb1 = (32 + m) * RROW;       // N-tile 1: x = 32 + m

    f32x16 acc0 = {};
    f32x16 acc1 = {};
    for (int s = 0; s < ns; ++s) {
        const int e = ebase + 16 * s;
        union { unsigned int u[4]; f16x8 h; } A;
        A.u[0] = w2v[e];     A.u[1] = w2v[e + 2];
        A.u[2] = w2v[e + 4]; A.u[3] = w2v[e + 6];
        const int ph = ((cb0 + 2 * s) ^ key) << 3;
        const f16x8 bf0 = *(const f16x8*)(sh + bb0 + ph);
        const f16x8 bf1 = *(const f16x8*)(sh + bb1 + ph);
        acc0 = __builtin_amdgcn_mfma_f32_32x32x16_f16(A.h, bf0, acc0, 0, 0, 0);
        acc1 = __builtin_amdgcn_mfma_f32_32x32x16_f16(A.h, bf1, acc1, 0, 0, 0);
    }

    __half* tb = tmp + img + (size_t)(y0 + 32 * tau) * W_ + x0 + m;
    #pragma unroll
    for (int reg = 0; reg < 16; ++reg) {
        const int row = (reg & 3) + 8 * (reg >> 2) + 4 * g;
        tb[(size_t)row * W_]      = __float2half(acc0[reg]);
        tb[(size_t)row * W_ + 32] = __float2half(acc1[reg]);
    }
}

// ---------------- horizontal pass (MFMA) ----------------
// Block: (bc, y0 = 64-row chunk, x0 = 128-col strip). LDS holds tmp rows
// with reflected x-halo: sh[row][i'], i' = global_x - (x0 - r_pad),
// chunk-XOR-swizzled by (row & 3). Image is the A operand (row reads),
// Toeplitz weights are the B operand (same per-lane w2 formula as pass1).
__global__ __launch_bounds__(256, 4) void k_pass2(const __half* __restrict__ tmp,
                                                  const unsigned int* __restrict__ gw2,
                                                  const int* __restrict__ rad,
                                                  float* __restrict__ out) {
    __shared__ __align__(16) unsigned short sh[SROW * RROW];
    __shared__ unsigned int w2v[NW];
    const int tid = threadIdx.x;
    const int bid = blockIdx.x;
    const int bc  = bid >> 5;
    const int rem = bid & 31;
    const int y0  = (rem >> 2) << 6;       // 8 y-chunks of 64
    const int x0  = (rem & 3) << 7;        // 4 x-chunks of 128
    const int b   = bc / C_;
    const size_t img = (size_t)bc * (H_ * (size_t)W_);

    const int r   = rad[b];
    const int rp  = (r + 7) & ~7;
    const int ns  = (r + rp + 32 + 15) >> 4;
    const int NC  = 12 + 2 * ns;           // staged 8-half chunks (<= 36)
    const int i0g = x0 - rp;               // 8-aligned global start

    if (tid < NW) w2v[tid] = gw2[b * NW + tid];

    {   // stage 64 rows; aligned uint4 interior, per-half reflect at edges
        const int row  = tid >> 2;         // 0..63
        const int cq   = tid & 3;
        const __half* grow = tmp + img + (size_t)(y0 + row) * W_;
        const int rkey = row & 3;
        for (int c = cq; c < NC; c += 4) {
            const int gi = i0g + c * 8;
            const int hidx = row * RROW + ((c ^ rkey) << 3);
            if (gi >= 0 && gi + 8 <= W_) {
                *(int4*)(sh + hidx) = *(const int4*)(grow + gi);
            } else {
                #pragma unroll
                for (int j = 0; j < 8; ++j)
                    sh[hidx + j] = __half_as_ushort(grow[refl(gi + j)]);
            }
        }
    }
    __syncthreads();

    const int l   = tid & 63;
    const int w   = tid >> 6;
    const int m   = l & 31;
    const int g   = l >> 5;
    const int tau = w >> 1;                // y-tile (2 of 32 rows)
    const int nup = (w & 1) * 2;           // N-tiles {nup, nup+1}
    const int ebase = WOFF + 8 * g - rp - m;
    const int arow  = 32 * tau + m;
    const int abase = arow * RROW;
    const int akey  = arow & 3;            // = m & 3
    const int ca0   = 4 * nup + g;         // i'-chunk = 4*nu + 2s + g

    f32x16 acc0 = {};
    f32x16 acc1 = {};
    for (int s = 0; s < ns; ++s) {
        const int e = ebase + 16 * s;
        union { unsigned int u[4]; f16x8 h; } Wf;
        Wf.u[0] = w2v[e];     Wf.u[1] = w2v[e + 2];
        Wf.u[2] = w2v[e + 4]; Wf.u[3] = w2v[e + 6];
        const int c = ca0 + 2 * s;
        const f16x8 af0 = *(const f16x8*)(sh + abase + ((c ^ akey) << 3));
        const f16x8 af1 = *(const f16x8*)(sh + abase + (((c + 4) ^ akey) << 3));
        acc0 = __builtin_amdgcn_mfma_f32_32x32x16_f16(af0, Wf.h, acc0, 0, 0, 0);
        acc1 = __builtin_amdgcn_mfma_f32_32x32x16_f16(af1, Wf.h, acc1, 0, 0, 0);
    }

    float* ob = out + img + (size_t)(y0 + 32 * tau) * W_ + x0 + 32 * nup + m;
    #pragma unroll
    for (int reg = 0; reg < 16; ++reg) {
        const int row = (reg & 3) + 8 * (reg >> 2) + 4 * g;
        ob[(size_t)row * W_]      = acc0[reg];
        ob[(size_t)row * W_ + 32] = acc1[reg];
    }
}

extern "C" void kernel_launch(void* const* d_in, const int* in_sizes, int n_in,
                              void* d_out, int out_size, void* d_ws, size_t ws_size,
                              hipStream_t stream) {
    const float* x     = (const float*)d_in[0];
    const float* sig   = (const float*)d_in[1];
    const int*   steps = (const int*)d_in[2];
    float* out = (float*)d_out;

    char* ws = (char*)d_ws;
    int*          rad = (int*)ws;                       // 256 B
    unsigned int* gw2 = (unsigned int*)(ws + 1024);     // 57344 B
    __half*       tmp = (__half*)(ws + 65536);          // 100663296 B

    k_weights<<<B_, 256, 0, stream>>>(sig, steps, rad, gw2);
    k_pass1<<<B_ * C_ * 32, 256, 0, stream>>>(x, gw2, rad, tmp);
    k_pass2<<<B_ * C_ * 32, 256, 0, stream>>>(tmp, gw2, rad, out);
}

// Round 2
// 398.262 us; speedup vs baseline: 1.2781x; 1.0549x over previous
//
#include <hip/hip_runtime.h>
#include <hip/hip_fp16.h>

// GaussianBlur as banded-Toeplitz GEMM on matrix cores, round 3.
// R4: two kernels only (weights folded into both passes).
//   pass1: 256-row y-chunks x 64-col strips, transposed f16 LDS staging
//          (chunk-XOR swizzle), one Toeplitz weight A-frag feeds 4 MFMAs
//          (2 y-tiles x 2 n-tiles) per k-step. XCD-chunked block swizzle.
//   pass2: full-width rows (32 rows x 672 staged halves), reflected x-halo
//          filled LDS->LDS (reflected source is always staged interior),
//          weight B-frag shared across 4 n-tiles per wave per k-step.
// ws: tmp f16 image at offset 0 (100663296 B).

#define B_   64
#define C_   3
#define H_   512
#define W_   512
#define RMAX 80
#define NW   224     // w2 pair-table entries, d in [-112, 111]
#define WOFF 112
#define RROW1 416    // pass1: LDS halfs per x-col (i' capacity, 224+16*12)
#define IW2   672    // pass2: LDS halfs per row (480 + 16*12)

typedef float    f32x16 __attribute__((ext_vector_type(16)));
typedef _Float16 f16x8  __attribute__((ext_vector_type(8)));

__device__ __forceinline__ int refl(int g) {
    int a = g < 0 ? -g : g;        // reflect (no edge repeat)
    int c = 1022 - a;              // 2*(H-1) - a
    return a < c ? a : c;
}

// Per-block weight build: w2v[t] = halves( W(t-112), W(t-111) ), radius r.
// scr/red overlap the staging LDS (safe: fully consumed before staging).
__device__ __forceinline__ int make_weights(float sigma, float* scr, float* red,
                                            unsigned int* w2v, int tid) {
    const int d = tid - 128;                 // [-128, 127] covers [-80, 80]
    float e = 0.f;
    if (d >= -RMAX && d <= RMAX) {
        const float u = (float)d / sigma;
        e = expf(-0.5f * u * u);
    }
    scr[tid] = e;
    red[tid] = e;
    __syncthreads();
    for (int s = 128; s > 0; s >>= 1) {
        if (tid < s) red[tid] += red[tid + s];
        __syncthreads();
    }
    const float inv = 1.0f / red[0];
    int r = (int)ceilf(6.0f * sigma);        // tail beyond 6 sigma < 7e-10
    if (r > RMAX) r = RMAX;
    if (r < 1)    r = 1;
    if (tid < NW) {
        const int d0 = tid - 112;
        const float w0 = (d0     >= -r && d0     <= r) ? scr[tid + 16] * inv : 0.f;
        const float w1 = (d0 + 1 >= -r && d0 + 1 <= r) ? scr[tid + 17] * inv : 0.f;
        w2v[tid] = (unsigned int)__half_as_ushort(__float2half(w0)) |
                   ((unsigned int)__half_as_ushort(__float2half(w1)) << 16);
    }
    __syncthreads();                         // scr reads done -> staging may reuse
    return r;
}

// ---------------- vertical pass ----------------
// Block: (bc, y0 = 256-row chunk, x0 = 64-col strip). sh[x][i'] transposed,
// i' = global_row - (y0 - rp), 16B-chunk index XOR-swizzled by (x & 3).
// Wave w handles y-tiles {w, w+4}, both 32-col n-tiles, sharing one
// Toeplitz weight A-fragment per k-step (tile-invariant).
__global__ __launch_bounds__(256) void k_pass1(const float* __restrict__ x,
                                               const float* __restrict__ sig,
                                               const int* __restrict__ steps,
                                               __half* __restrict__ tmp) {
    __shared__ __align__(16) unsigned short sh[64 * RROW1];   // 53248 B
    __shared__ unsigned int w2v[NW];                          // 896 B
    const int tid = threadIdx.x;
    int bid = blockIdx.x;
    bid = ((bid & 7) * 384) + (bid >> 3);    // XCD chunking (3072 % 8 == 0)
    const int bc  = bid >> 4;
    const int rem = bid & 15;
    const int y0  = (rem >> 3) << 8;         // 0, 256
    const int x0  = (rem & 7) << 6;          // 0..448 step 64
    const int b   = bc / C_;
    const size_t img = (size_t)bc * (H_ * (size_t)W_);

    const float sigma = sig[steps[b]] + 1e-6f;
    float* scr = (float*)sh;
    const int r  = make_weights(sigma, scr, scr + 256, w2v, tid);
    const int rp = (r + 7) & ~7;
    const int ns = (r + rp + 47) >> 4;       // K-steps per tile (16*ns >= r+rp+32)
    const int Rr = 224 + 16 * ns;            // staged rows (<= 416)
    const int ystart = y0 - rp;

    {   // stage transposed + row-reflected: row-pairs x 4-col groups
        const int p0 = tid & 15;             // row-pair id (mod 16)
        const int x4 = tid >> 4;             // col group (4 cols)
        const float* gsrc = x + img + (size_t)(x0 + x4 * 4);
        const int i7 = (2 * p0) & 7;         // (i0 & 7) invariant per thread
        for (int pr = p0; 2 * pr < Rr; pr += 16) {
            const int i0  = 2 * pr;
            const int gy0 = refl(ystart + i0);
            const int gy1 = refl(ystart + i0 + 1);
            const float4 va = *(const float4*)(gsrc + (size_t)gy0 * W_);
            const float4 vb = *(const float4*)(gsrc + (size_t)gy1 * W_);
            const float* fa = (const float*)&va;
            const float* fb = (const float*)&vb;
            const int c = i0 >> 3;
            #pragma unroll
            for (int q = 0; q < 4; ++q) {
                const int xq = x4 * 4 + q;
                const int hidx = xq * RROW1 + ((c ^ (xq & 3)) << 3) + i7;
                *(__half2*)(sh + hidx) = __floats2half2_rn(fa[q], fb[q]);
            }
        }
    }
    __syncthreads();

    const int l   = tid & 63;
    const int wv_ = tid >> 6;                // wave id
    const int m   = l & 31;
    const int g   = l >> 5;                  // k-group
    const int key = m & 3;
    const int ebase = WOFF + 8 * g - rp - m;
    const int cA  = 4 * wv_ + g;             // y-tile wv_
    const int cB  = 4 * (wv_ + 4) + g;       // y-tile wv_+4
    const unsigned short* shm0 = sh + m * RROW1;
    const unsigned short* shm1 = sh + (32 + m) * RROW1;

    f32x16 a0 = {}, a1 = {}, a2 = {}, a3 = {};
    for (int s = 0; s < ns; ++s) {
        const int e = ebase + 16 * s;
        union { unsigned int u[4]; f16x8 h; } A;
        A.u[0] = w2v[e];     A.u[1] = w2v[e + 2];
        A.u[2] = w2v[e + 4]; A.u[3] = w2v[e + 6];
        const int phA = ((cA + 2 * s) ^ key) << 3;
        const int phB = ((cB + 2 * s) ^ key) << 3;
        const f16x8 b00 = *(const f16x8*)(shm0 + phA);
        const f16x8 b01 = *(const f16x8*)(shm1 + phA);
        const f16x8 b10 = *(const f16x8*)(shm0 + phB);
        const f16x8 b11 = *(const f16x8*)(shm1 + phB);
        a0 = __builtin_amdgcn_mfma_f32_32x32x16_f16(A.h, b00, a0, 0, 0, 0);
        a1 = __builtin_amdgcn_mfma_f32_32x32x16_f16(A.h, b01, a1, 0, 0, 0);
        a2 = __builtin_amdgcn_mfma_f32_32x32x16_f16(A.h, b10, a2, 0, 0, 0);
        a3 = __builtin_amdgcn_mfma_f32_32x32x16_f16(A.h, b11, a3, 0, 0, 0);
    }

    __half* tb0 = tmp + img + (size_t)(y0 + 32 * wv_) * W_ + x0 + m;
    __half* tb1 = tmp + img + (size_t)(y0 + 32 * (wv_ + 4)) * W_ + x0 + m;
    #pragma unroll
    for (int reg = 0; reg < 16; ++reg) {
        const int row = (reg & 3) + 8 * (reg >> 2) + 4 * g;
        tb0[(size_t)row * W_]      = __float2half(a0[reg]);
        tb0[(size_t)row * W_ + 32] = __float2half(a1[reg]);
        tb1[(size_t)row * W_]      = __float2half(a2[reg]);
        tb1[(size_t)row * W_ + 32] = __float2half(a3[reg]);
    }
}

// ---------------- horizontal pass ----------------
// Block: (bc, y0 = 32-row chunk, full 512-col width). sh[row][i'],
// i' = global_x + rp, chunk-XOR-swizzled by (row & 3). Interior staged with
// aligned int4; reflected halos copied LDS->LDS (source always interior).
// Wave w handles n-tiles {4w..4w+3}; weight B-frag shared across all 4.
__global__ __launch_bounds__(256) void k_pass2(const __half* __restrict__ tmp,
                                               const float* __restrict__ sig,
                                               const int* __restrict__ steps,
                                               float* __restrict__ out) {
    __shared__ __align__(16) unsigned short sh[32 * IW2];     // 43008 B
    __shared__ unsigned int w2v[NW];
    const int tid = threadIdx.x;
    const int bid = blockIdx.x;
    const int bc  = bid >> 4;
    const int y0  = (bid & 15) << 5;         // 16 chunks of 32 rows
    const int b   = bc / C_;
    const size_t img = (size_t)bc * (H_ * (size_t)W_);

    const float sigma = sig[steps[b]] + 1e-6f;
    float* scr = (float*)sh;
    const int r  = make_weights(sigma, scr, scr + 256, w2v, tid);
    const int rp = (r + 7) & ~7;
    const int ns = (r + rp + 47) >> 4;

    const int row  = tid >> 3;               // 0..31
    const int cq   = tid & 7;                // 8 threads per row
    const int rkey = row & 3;
    {   // interior: 64 aligned int4 chunks per row, i' = rp + 8k
        const __half* grow = tmp + img + (size_t)(y0 + row) * W_;
        const int cb = rp >> 3;
        for (int k = cq; k < 64; k += 8) {
            const int c = cb + k;
            *(int4*)(sh + row * IW2 + ((c ^ rkey) << 3)) =
                *(const int4*)(grow + k * 8);
        }
    }
    __syncthreads();
    {   // halos from staged interior (reflect): left [0,rp), right [512+rp, 480+16ns)
        const int nh = 16 * ns - 32;         // halo halfs per row (<= 160)
        const int rbase = row * IW2;
        for (int e = cq; e < nh; e += 8) {
            const int ip = e < rp ? e : e + 512;
            const int gx = ip - rp;
            const int is = refl(gx) + rp;    // always in staged interior
            const unsigned short v =
                sh[rbase + (((is >> 3) ^ rkey) << 3) + (is & 7)];
            sh[rbase + (((ip >> 3) ^ rkey) << 3) + (ip & 7)] = v;
        }
    }
    __syncthreads();

    const int l   = tid & 63;
    const int wv_ = tid >> 6;
    const int m   = l & 31;                  // image row (A) / out col offset (D)
    const int g   = l >> 5;
    const int akey  = m & 3;
    const int ebase = WOFF + 8 * g - rp - m;
    const unsigned short* shm = sh + m * IW2;
    const int c0 = 16 * wv_ + g;             // n-tile base chunk (nu = 4*wv_)

    f32x16 a0 = {}, a1 = {}, a2 = {}, a3 = {};
    for (int s = 0; s < ns; ++s) {
        const int e = ebase + 16 * s;
        union { unsigned int u[4]; f16x8 h; } Wf;
        Wf.u[0] = w2v[e];     Wf.u[1] = w2v[e + 2];
        Wf.u[2] = w2v[e + 4]; Wf.u[3] = w2v[e + 6];
        const int cs = c0 + 2 * s;
        const f16x8 f0 = *(const f16x8*)(shm + (((cs     ) ^ akey) << 3));
        const f16x8 f1 = *(const f16x8*)(shm + (((cs +  4) ^ akey) << 3));
        const f16x8 f2 = *(const f16x8*)(shm + (((cs +  8) ^ akey) << 3));
        const f16x8 f3 = *(const f16x8*)(shm + (((cs + 12) ^ akey) << 3));
        a0 = __builtin_amdgcn_mfma_f32_32x32x16_f16(f0, Wf.h, a0, 0, 0, 0);
        a1 = __builtin_amdgcn_mfma_f32_32x32x16_f16(f1, Wf.h, a1, 0, 0, 0);
        a2 = __builtin_amdgcn_mfma_f32_32x32x16_f16(f2, Wf.h, a2, 0, 0, 0);
        a3 = __builtin_amdgcn_mfma_f32_32x32x16_f16(f3, Wf.h, a3, 0, 0, 0);
    }

    float* ob = out + img + (size_t)y0 * W_ + 128 * wv_ + m;
    #pragma unroll
    for (int reg = 0; reg < 16; ++reg) {
        const int orow = (reg & 3) + 8 * (reg >> 2) + 4 * g;
        float* orp_ = ob + (size_t)orow * W_;
        orp_[0]  = a0[reg];
        orp_[32] = a1[reg];
        orp_[64] = a2[reg];
        orp_[96] = a3[reg];
    }
}

extern "C" void kernel_launch(void* const* d_in, const int* in_sizes, int n_in,
                              void* d_out, int out_size, void* d_ws, size_t ws_size,
                              hipStream_t stream) {
    const float* x     = (const float*)d_in[0];
    const float* sig   = (const float*)d_in[1];
    const int*   steps = (const int*)d_in[2];
    float* out = (float*)d_out;
    __half* tmp = (__half*)d_ws;             // 100663296 B

    k_pass1<<<B_ * C_ * 16, 256, 0, stream>>>(x, sig, steps, tmp);
    k_pass2<<<B_ * C_ * 16, 256, 0, stream>>>(tmp, sig, steps, out);
}